// Round 14
// baseline (5682.423 us; speedup 1.0000x reference)
//
#include <hip/hip_runtime.h>
#include <hip/hip_bf16.h>

#define LN_EPS 1e-5f

typedef __attribute__((ext_vector_type(4))) float    f32x4;
typedef __attribute__((ext_vector_type(8))) _Float16 f16x8;
typedef __attribute__((ext_vector_type(4))) unsigned u32x4;

// fast transcendentals (v_exp based)
__device__ __forceinline__ float fsig(float x){
  return 1.0f/(1.0f + __expf(-x));
}
__device__ __forceinline__ float ftanh(float x){
  float xx = fminf(fmaxf(x, -15.f), 15.f);
  float e = __expf(2.f*xx);
  return (e - 1.f)/(e + 1.f);
}

__device__ __forceinline__ float agent_load_f(const float* p){
  return __hip_atomic_load((float*)p, __ATOMIC_RELAXED, __HIP_MEMORY_SCOPE_AGENT);
}
__device__ __forceinline__ void agent_store_f(float* p, float v){
  __hip_atomic_store(p, v, __ATOMIC_RELAXED, __HIP_MEMORY_SCOPE_AGENT);
}

// ---------------------------------------------------------------------------
// bn1
// ---------------------------------------------------------------------------
__global__ void k_bn1_stats(const float* __restrict__ x, float* __restrict__ stats){
  int tid = threadIdx.x;
  int cg = tid >> 3, ro = tid & 7;
  int c4 = cg * 4;
  float s[4] = {0,0,0,0}, q[4] = {0,0,0,0};
  int rbase = blockIdx.x * 64;
  for (int i = 0; i < 8; ++i){
    int row = rbase + i*8 + ro;
    f32x4 v = *(const f32x4*)(x + (size_t)row*128 + c4);
    #pragma unroll
    for (int e=0;e<4;e++){ s[e]+=v[e]; q[e]+=v[e]*v[e]; }
  }
  #pragma unroll
  for (int o=1;o<8;o<<=1){
    #pragma unroll
    for (int e=0;e<4;e++){ s[e]+=__shfl_xor(s[e],o); q[e]+=__shfl_xor(q[e],o); }
  }
  if (ro==0){
    #pragma unroll
    for (int e=0;e<4;e++){
      atomicAdd(&stats[c4+e], s[e]);
      atomicAdd(&stats[128+c4+e], q[e]);
    }
  }
}

__global__ void k_bn1_fin(const float* __restrict__ stats, const float* __restrict__ gamma,
                          const float* __restrict__ beta, float* __restrict__ ss){
  int c = threadIdx.x;
  if (c < 128){
    float N = 16384.0f;
    float mean = stats[c]/N;
    float var  = stats[128+c]/N - mean*mean;
    float scale = gamma[c] * rsqrtf(var + LN_EPS);
    ss[c] = scale;
    ss[128+c] = beta[c] - mean*scale;
  }
}

// f32 -> f16 elementwise
__global__ void k_cvt_f16(const float* __restrict__ s, _Float16* __restrict__ d, int n){
  for (int i = blockIdx.x*blockDim.x + threadIdx.x; i < n; i += gridDim.x*blockDim.x)
    d[i] = (_Float16)s[i];
}

// pack whh [2][2048][512] f32 -> fragment-linear f16
// wpk[(dir*4+gate)][kt=16][c16=32][lane=64][8]
__global__ void k_pack_whh(const float* __restrict__ whh, _Float16* __restrict__ wpk){
  size_t i = (size_t)blockIdx.x*256 + threadIdx.x;     // over 2*2048*512
  int k = (int)(i & 511);
  size_t ci = i >> 9;
  int col = (int)(ci & 2047);
  int dirr = (int)(ci >> 11);
  int gate = col >> 9, cig = col & 511, c16 = cig >> 4, lc = cig & 15;
  int kt = k >> 5, ksub = k & 31, hi = ksub >> 3, j = ksub & 7;
  size_t dst = ((((size_t)(dirr*4+gate)*16 + kt)*32 + c16)*64 + (hi*16+lc))*8 + j;
  wpk[dst] = (_Float16)whh[i];
}

// ---------------------------------------------------------------------------
// Single-pass f16 GEMM: C[M][N] = A[M][K] * B[N][K]^T, C f16, fp32 accumulate.
// ---------------------------------------------------------------------------
__global__ __launch_bounds__(256) void gemm_f16(const float* __restrict__ A,
                                                const _Float16* __restrict__ Bp,
                                                _Float16* __restrict__ C,
                                                int M, int N, int K,
                                                int a_mode, const float* __restrict__ ss){
  __shared__ __align__(16) _Float16 As[128*32];
  __shared__ __align__(16) _Float16 Bs[128*32];
  int n0 = blockIdx.x * 128, m0 = blockIdx.y * 128;
  int tid = threadIdx.x, lane = tid & 63, wave = tid >> 6;
  int wm = wave >> 1, wn = wave & 1;
  f32x4 acc[4][4] = {};
  int r = tid >> 2, sseg = tid & 3;
  for (int kt = 0; kt < K; kt += 32){
    #pragma unroll
    for (int half = 0; half < 2; ++half){
      int m = m0 + half*64 + r;
      const float* src;
      if (a_mode){
        int t = m >> 5, b = m & 31;
        src = A + ((size_t)(b*512 + t))*128 + kt + sseg*8;
      } else {
        src = A + (size_t)m*K + kt + sseg*8;
      }
      f32x4 v0 = *(const f32x4*)src;
      f32x4 v1 = *(const f32x4*)(src + 4);
      f16x8 vh;
      #pragma unroll
      for (int e=0;e<4;e++){
        float f0 = v0[e], f1 = v1[e];
        if (a_mode){
          int k = kt + sseg*8;
          f0 = f0*ss[k+e]   + ss[128+k+e];
          f1 = f1*ss[k+4+e] + ss[128+k+4+e];
        }
        vh[e] = (_Float16)f0; vh[4+e] = (_Float16)f1;
      }
      *(f16x8*)&As[(half*64+r)*32 + sseg*8] = vh;
      u32x4 bv = *(const u32x4*)(Bp + (size_t)(n0 + half*64 + r)*K + kt + sseg*8);
      *(u32x4*)&Bs[(half*64+r)*32 + sseg*8] = bv;
    }
    __syncthreads();
    f16x8 af[4], bf[4];
    int k8 = (lane >> 4) * 8;
    int ra = wm*64 + (lane & 15), rb = wn*64 + (lane & 15);
    #pragma unroll
    for (int mi=0;mi<4;mi++) af[mi] = *(const f16x8*)&As[(ra + mi*16)*32 + k8];
    #pragma unroll
    for (int ni=0;ni<4;ni++) bf[ni] = *(const f16x8*)&Bs[(rb + ni*16)*32 + k8];
    #pragma unroll
    for (int mi=0;mi<4;mi++)
      #pragma unroll
      for (int ni=0;ni<4;ni++)
        acc[mi][ni] = __builtin_amdgcn_mfma_f32_16x16x32_f16(af[mi], bf[ni], acc[mi][ni], 0, 0, 0);
    __syncthreads();
  }
  #pragma unroll
  for (int mi=0;mi<4;mi++)
    #pragma unroll
    for (int ni=0;ni<4;ni++){
      int col  = n0 + wn*64 + ni*16 + (lane & 15);
      int row0 = m0 + wm*64 + mi*16 + (lane >> 4)*4;
      #pragma unroll
      for (int rr=0;rr<4;rr++)
        C[(size_t)(row0+rr)*N + col] = (_Float16)acc[mi][ni][rr];
    }
}

// ---------------------------------------------------------------------------
// LSTM, weights-in-registers, small-group exchange, per-wave flags (5 syncs):
// 256 blocks = bq(16) x dir(2) x gate(4) x half(2); 2 batch rows, 256 cols.
// Weights: 32 f16x8 = 128 VGPRs, asm "+v" pinned.
// Per step: GEMV -> publish tile -> S1(red) -> stats store -> per-wave
// vmcnt drain + per-wave flag word (no RMW, no block barrier) ->
// poll 7 siblings x 8 wave-flags (tid<56) -> S3 -> read tiles + stats(tid<8)
// -> S4 -> LN+cell (2b) -> S5 -> c-LN combine -> h to LDS; out store spread
// across all 8 blocks (64 cols each). -> S6.
// chunk layout (floats): [2 b][256 cols] + [2 b][2 stats]  (stride 516)
// flags: [256 blocks][64], words 0..7 = per-wave monotonic step counters.
// ---------------------------------------------------------------------------
#define CHUNK 516

__global__ __launch_bounds__(512, 1) void lstm_fast(
    const _Float16* __restrict__ xp,     // [16384][4096]
    const _Float16* __restrict__ wpk,    // [8 slices][16][32][64][8]
    const float* __restrict__ gg, const float* __restrict__ gb,   // [2][2048]
    const float* __restrict__ cgam, const float* __restrict__ cbet, // [2][512]
    float* __restrict__ out,             // [16384][1024]
    float* __restrict__ tf,              // [32grp][2buf][8chunk][CHUNK]
    unsigned* __restrict__ flags)        // [256*64]
{
  int blk = blockIdx.x;
  int sub = blk & 15;                    // (dir,gate,half) -> XCD spread
  int bq = blk >> 4;                     // 0..15, 2 batch rows each
  int dir = sub >> 3, gate = (sub >> 1) & 3, half = sub & 1;
  int tid = threadIdx.x, lane = tid & 63, wv = tid >> 6;
  int b0 = bq * 2;
  int grp = bq*2 + dir;                  // 0..31
  int blkbase = (bq << 4) | (dir << 3);
  int own_sub = gate*2 + half;           // 0..7

  __shared__ __align__(16) _Float16 hfrag[16*64*8];   // 16KB A-fragments (rows 0..1 used)
  __shared__ float c_s[2][512];                        // 4KB
  __shared__ float red[8][2][2];
  __shared__ float redc[8][2][2];
  __shared__ float lnstat[8][2];

  for (int i = tid; i < 16*64*8; i += 512) hfrag[i] = (_Float16)0.f;
  for (int i = tid; i < 2*512;  i += 512) c_s[i>>9][i&511] = 0.f;
  __syncthreads();

  // ---- hoist loop-invariant LN/cell params ----
  int j = tid;
  float g0s = gg[dir*2048 + j],        g0b = gb[dir*2048 + j];
  float g1s = gg[dir*2048 + 512 + j],  g1b = gb[dir*2048 + 512 + j];
  float g2s = gg[dir*2048 + 1024 + j], g2b = gb[dir*2048 + 1024 + j];
  float g3s = gg[dir*2048 + 1536 + j], g3b = gb[dir*2048 + 1536 + j];
  float cgv = cgam[dir*512 + j],       cbv = cbet[dir*512 + j];
  int outsel = (j >> 6);                 // block own_sub stores cols j>>6==own_sub

  // ---- load weight slice into registers: c16 = half*16 + wv*2 + {0,1} ----
  const _Float16* wbase = wpk + (size_t)(dir*4 + gate) * (16*32*64*8);
  int c16a = half*16 + wv*2, c16b = c16a + 1;
  f16x8 wA[16], wB[16];
  #pragma unroll
  for (int kt = 0; kt < 16; ++kt){
    wA[kt] = *(const f16x8*)&wbase[(((size_t)kt*32 + c16a)*64 + lane)*8];
    wB[kt] = *(const f16x8*)&wbase[(((size_t)kt*32 + c16b)*64 + lane)*8];
  }

  for (int t = 0; t < 512; ++t){
    // pin all 32 fragments: asm "redefines" them each iteration -> no remat
    asm volatile("" : "+v"(wA[0]), "+v"(wA[1]), "+v"(wA[2]), "+v"(wA[3]),
                      "+v"(wA[4]), "+v"(wA[5]), "+v"(wA[6]), "+v"(wA[7]));
    asm volatile("" : "+v"(wA[8]), "+v"(wA[9]), "+v"(wA[10]), "+v"(wA[11]),
                      "+v"(wA[12]), "+v"(wA[13]), "+v"(wA[14]), "+v"(wA[15]));
    asm volatile("" : "+v"(wB[0]), "+v"(wB[1]), "+v"(wB[2]), "+v"(wB[3]),
                      "+v"(wB[4]), "+v"(wB[5]), "+v"(wB[6]), "+v"(wB[7]));
    asm volatile("" : "+v"(wB[8]), "+v"(wB[9]), "+v"(wB[10]), "+v"(wB[11]),
                      "+v"(wB[12]), "+v"(wB[13]), "+v"(wB[14]), "+v"(wB[15]));
    int pos = dir ? (511 - t) : t;
    int buf = t & 1;
    // ---- xp loads (independent of h) ----
    float xv0[2], xv1[2];
    if (lane < 16){
      const _Float16* xb = xp + (size_t)(pos*32 + b0)*4096 + dir*2048 + gate*512 + half*256;
      #pragma unroll
      for (int r = 0; r < 2; ++r){
        xv0[r] = (float)xb[(size_t)r*4096 + (wv*2)*16 + lane];
        xv1[r] = (float)xb[(size_t)r*4096 + (wv*2)*16 + lane + 16];
      }
    }
    // ---- GEMV: pure-register MFMA (32 MFMA) ----
    f32x4 acc0 = {}, acc1 = {};
    #pragma unroll
    for (int kt = 0; kt < 16; ++kt){
      f16x8 afrag = *(const f16x8*)&hfrag[(kt*64 + lane)*8];
      acc0 = __builtin_amdgcn_mfma_f32_16x16x32_f16(afrag, wA[kt], acc0, 0, 0, 0);
      acc1 = __builtin_amdgcn_mfma_f32_16x16x32_f16(afrag, wB[kt], acc1, 0, 0, 0);
    }
    // ---- pre-LN + publish chunk [2b][256col] + stats partials ----
    float* chk = tf + ((size_t)(grp*2 + buf)*8 + own_sub)*CHUNK;
    float s[2] = {0,0}, q[2] = {0,0};
    if (lane < 16){
      int cA = (wv*2)*16 + lane, cB = cA + 16;     // local cols 0..255
      #pragma unroll
      for (int r = 0; r < 2; ++r){
        float v0 = acc0[r] + xv0[r];
        float v1 = acc1[r] + xv1[r];
        agent_store_f(chk + r*256 + cA, v0);
        agent_store_f(chk + r*256 + cB, v1);
        s[r] = v0 + v1; q[r] = v0*v0 + v1*v1;
      }
    }
    #pragma unroll
    for (int o = 1; o < 16; o <<= 1){
      #pragma unroll
      for (int r = 0; r < 2; ++r){ s[r] += __shfl_xor(s[r], o); q[r] += __shfl_xor(q[r], o); }
    }
    if (lane == 0){
      #pragma unroll
      for (int r = 0; r < 2; ++r){ red[wv][r][0] = s[r]; red[wv][r][1] = q[r]; }
    }
    __syncthreads();                 // S1: red ready
    if (tid < 4){
      int b = tid >> 1, wh = tid & 1;
      float S = 0.f;
      #pragma unroll
      for (int w8 = 0; w8 < 8; ++w8) S += red[w8][b][wh];
      agent_store_f(chk + 512 + b*2 + wh, S);
    }
    // per-wave drain + per-wave flag word (plain sc1 store, no RMW, no barrier)
    asm volatile("s_waitcnt vmcnt(0)" ::: "memory");
    if (lane == 0)
      __hip_atomic_store(&flags[blk*64 + wv], (unsigned)(t+1),
                         __ATOMIC_RELAXED, __HIP_MEMORY_SCOPE_AGENT);
    // poll 7 siblings x 8 wave-flags
    if (tid < 56){
      int sb = tid >> 3, w8 = tid & 7;
      int idx = sb < own_sub ? sb : sb + 1;
      int sblk = blkbase + idx;
      while (__hip_atomic_load(&flags[sblk*64 + w8], __ATOMIC_RELAXED, __HIP_MEMORY_SCOPE_AGENT)
             < (unsigned)(t+1)){ }
    }
    __syncthreads();                 // S3: all sibling data visible
    // ---- read: tiles (all threads, 8 loads) + stats (tid<8) ----
    const float* gbase = tf + ((size_t)(grp*2 + buf)*8)*CHUNK;
    int hf = j >> 8, cc = j & 255;       // half, col-in-half for column j
    float p[4][2];
    #pragma unroll
    for (int g = 0; g < 4; ++g){
      const float* cp = gbase + (size_t)(g*2 + hf)*CHUNK + cc;
      #pragma unroll
      for (int b = 0; b < 2; ++b) p[g][b] = agent_load_f(cp + b*256);
    }
    if (tid < 8){
      int g = tid >> 1, b = tid & 1;
      float S = 0.f, Q = 0.f;
      #pragma unroll
      for (int hh = 0; hh < 2; ++hh){
        S += agent_load_f(gbase + (size_t)(g*2 + hh)*CHUNK + 512 + b*2);
        Q += agent_load_f(gbase + (size_t)(g*2 + hh)*CHUNK + 512 + b*2 + 1);
      }
      float mean = S*(1.0f/512.0f);
      float var  = Q*(1.0f/512.0f) - mean*mean;
      lnstat[tid][0] = mean; lnstat[tid][1] = rsqrtf(var + LN_EPS);
    }
    __syncthreads();                 // S4: lnstat ready (p already in regs)
    // ---- LN + cell update (2 b per thread) ----
    float cs[2], cq2[2], ov[2], cnv[2];
    #pragma unroll
    for (int b = 0; b < 2; ++b){
      float pi = (p[0][b] - lnstat[0*2+b][0])*lnstat[0*2+b][1]*g0s + g0b;
      float pf = (p[1][b] - lnstat[1*2+b][0])*lnstat[1*2+b][1]*g1s + g1b;
      float pv = (p[2][b] - lnstat[2*2+b][0])*lnstat[2*2+b][1]*g2s + g2b;
      ov[b]    = (p[3][b] - lnstat[3*2+b][0])*lnstat[3*2+b][1]*g3s + g3b;
      float cn = fsig(pf)*c_s[b][j] + fsig(pi)*ftanh(pv);
      c_s[b][j] = cn; cnv[b] = cn;
      cs[b] = cn; cq2[b] = cn*cn;
    }
    #pragma unroll
    for (int o = 1; o < 64; o <<= 1){
      #pragma unroll
      for (int b = 0; b < 2; ++b){ cs[b] += __shfl_xor(cs[b], o); cq2[b] += __shfl_xor(cq2[b], o); }
    }
    if (lane == 0){
      #pragma unroll
      for (int b = 0; b < 2; ++b){ redc[wv][b][0] = cs[b]; redc[wv][b][1] = cq2[b]; }
    }
    __syncthreads();                 // S5: redc ready
    #pragma unroll
    for (int b = 0; b < 2; ++b){
      float S = 0.f, Q = 0.f;
      #pragma unroll
      for (int w8 = 0; w8 < 8; ++w8){ S += redc[w8][b][0]; Q += redc[w8][b][1]; }
      float mean = S*(1.0f/512.0f);
      float var  = Q*(1.0f/512.0f) - mean*mean;
      float rstd = rsqrtf(var + LN_EPS);
      float cl = (cnv[b] - mean)*rstd*cgv + cbv;
      float hv = fsig(ov[b]) * ftanh(cl);
      hfrag[(((j >> 5)*64) + ((j & 31) >> 3)*16 + b)*8 + (j & 7)] = (_Float16)hv;
      if (outsel == own_sub)
        out[(size_t)(pos*32 + b0 + b)*1024 + dir*512 + j] = hv;
    }
    __syncthreads();                 // S6: hfrag ready for next step
  }
}

// ---------------------------------------------------------------------------
__global__ void k_bn2_stats(const float* __restrict__ h1, float* __restrict__ stats){
  int tid = threadIdx.x;
  int c4 = tid*4;
  float s[4]={0,0,0,0}, q[4]={0,0,0,0};
  int rbase = blockIdx.x*64;
  for (int i=0;i<64;i++){
    f32x4 v = *(const f32x4*)(h1 + (size_t)(rbase+i)*1024 + c4);
    #pragma unroll
    for (int e=0;e<4;e++){ s[e]+=v[e]; q[e]+=v[e]*v[e]; }
  }
  #pragma unroll
  for (int e=0;e<4;e++){
    atomicAdd(&stats[c4+e], s[e]);
    atomicAdd(&stats[1024+c4+e], q[e]);
  }
}

__global__ void k_bn2_fin(const float* __restrict__ stats, const float* __restrict__ gamma,
                          const float* __restrict__ beta, float* __restrict__ ss){
  int c = blockIdx.x*256 + threadIdx.x;
  if (c < 1024){
    float N = 16384.0f;
    float mean = stats[c]/N;
    float var  = stats[1024+c]/N - mean*mean;
    float scale = gamma[c] * rsqrtf(var + LN_EPS);
    ss[c] = scale;
    ss[1024+c] = beta[c] - mean*scale;
  }
}

__global__ void k_att1(const float* __restrict__ h1, const float* __restrict__ ss,
                       const float* __restrict__ wom, const float* __restrict__ bom,
                       const float* __restrict__ uom, float* __restrict__ vu){
  __shared__ float tmp[4][64];
  int tid = threadIdx.x, wave = tid >> 6, ln = tid & 63;
  int part = ln/20, a = ln - part*20;
  bool active = (part < 3);
  for (int rr = 0; rr < 4; ++rr){
    int row = blockIdx.x*16 + wave*4 + rr;
    float acc = 0.0f;
    if (active){
      int n0 = part*342, n1 = (part==2) ? 1024 : (n0+342);
      for (int n = n0; n < n1; ++n){
        float hv = h1[(size_t)row*1024 + n]*ss[n] + ss[1024+n];
        acc += hv * wom[n*20 + a];
      }
    }
    tmp[wave][ln] = acc;
    __syncthreads();
    float pv = 0.0f;
    if (ln < 20){
      float v = tanhf(tmp[wave][ln] + tmp[wave][ln+20] + tmp[wave][ln+40] + bom[ln]);
      pv = v*uom[ln];
    }
    #pragma unroll
    for (int o=1;o<32;o<<=1) pv += __shfl_xor(pv, o);
    if (ln == 0) vu[row] = pv;
    __syncthreads();
  }
}

__global__ void k_att3(const float* __restrict__ h1, const float* __restrict__ ss,
                       const float* __restrict__ vu, float* __restrict__ out){
  __shared__ float al[512];
  __shared__ float red[4];
  int tid = threadIdx.x;
  int b = blockIdx.x >> 3, ch = blockIdx.x & 7;
  for (int t = tid; t < 512; t += 128) al[t] = vu[t*32 + b];
  __syncthreads();
  float m = -1e30f;
  for (int t = tid; t < 512; t += 128) m = fmaxf(m, al[t]);
  #pragma unroll
  for (int o=1;o<64;o<<=1) m = fmaxf(m, __shfl_xor(m,o));
  if ((tid & 63) == 0) red[tid>>6] = m;
  __syncthreads();
  m = fmaxf(red[0], red[1]);
  float s = 0.0f;
  for (int t = tid; t < 512; t += 128){ float e = expf(al[t]-m); al[t] = e; s += e; }
  #pragma unroll
  for (int o=1;o<64;o<<=1) s += __shfl_xor(s,o);
  if ((tid & 63) == 0) red[2 + (tid>>6)] = s;
  __syncthreads();
  float inv = 1.0f / (red[2] + red[3]);
  int n = ch*128 + tid;
  float acc = 0.0f;
  #pragma unroll 4
  for (int t = 0; t < 512; ++t) acc += al[t]*h1[(size_t)(t*32+b)*1024 + n];
  out[b*1024 + n] = acc*inv*ss[n] + ss[1024+n];
}

// ---------------------------------------------------------------------------
extern "C" void kernel_launch(void* const* d_in, const int* in_sizes, int n_in,
                              void* d_out, int out_size, void* d_ws, size_t ws_size,
                              hipStream_t stream){
  const float* x    = (const float*)d_in[0];
  const float* bn1g = (const float*)d_in[1];
  const float* bn1b = (const float*)d_in[2];
  const float* bn2g = (const float*)d_in[3];
  const float* bn2b = (const float*)d_in[4];
  const float* wih0 = (const float*)d_in[5];
  const float* whh0 = (const float*)d_in[6];
  const float* gg0  = (const float*)d_in[7];
  const float* gb0  = (const float*)d_in[8];
  const float* cg0  = (const float*)d_in[9];
  const float* cb0  = (const float*)d_in[10];
  const float* wih1 = (const float*)d_in[11];
  const float* whh1 = (const float*)d_in[12];
  const float* gg1  = (const float*)d_in[13];
  const float* gb1  = (const float*)d_in[14];
  const float* cg1  = (const float*)d_in[15];
  const float* cb1  = (const float*)d_in[16];
  const float* wom  = (const float*)d_in[17];
  const float* bom  = (const float*)d_in[18];
  const float* uom  = (const float*)d_in[19];
  float* out = (float*)d_out;

  char* w = (char*)d_ws;
  size_t off = 0;
  auto take = [&](size_t bytes)->void*{
    void* p = w + off;
    off += (bytes + 255) & ~(size_t)255;
    return p;
  };
  _Float16* xp = (_Float16*)take(16384ull*4096*2);      // 128 MB
  float* hA = (float*)take(16384ull*1024*4);            // 64 MB
  _Float16* w0h = (_Float16*)take(4096ull*128*2);       // 1 MB
  _Float16* w1h = (_Float16*)take(4096ull*1024*2);      // 8 MB
  _Float16* wpk0 = (_Float16*)take(2ull*2048*512*2);    // 4 MB
  _Float16* wpk1 = (_Float16*)take(2ull*2048*512*2);    // 4 MB
  float* tilesf = (float*)take(32ull*2*8*CHUNK*4);      // ~1.06 MB
  unsigned* flags = (unsigned*)take(256ull*64*4);       // 64 KB
  float* stats1 = (float*)take(256*4);
  float* ss1    = (float*)take(256*4);
  float* stats2 = (float*)take(2048*4);
  float* ss2    = (float*)take(2048*4);
  float* vu     = (float*)take(16384ull*4);
  (void)ws_size; (void)in_sizes; (void)n_in; (void)out_size;

  hipMemsetAsync(stats1, 0, 256*4, stream);
  hipMemsetAsync(stats2, 0, 2048*4, stream);

  k_bn1_stats<<<256,256,0,stream>>>(x, stats1);
  k_bn1_fin<<<1,128,0,stream>>>(stats1, bn1g, bn1b, ss1);
  k_cvt_f16<<<256,256,0,stream>>>(wih0, w0h, 4096*128);
  k_cvt_f16<<<2048,256,0,stream>>>(wih1, w1h, 4096*1024);
  k_pack_whh<<<8192,256,0,stream>>>(whh0, wpk0);
  k_pack_whh<<<8192,256,0,stream>>>(whh1, wpk1);

  // GEMM0: xp = bn1(x) @ w_ih0^T
  gemm_f16<<<dim3(32,128),256,0,stream>>>(x, w0h, xp, 16384, 4096, 128, 1, ss1);

  // ---- layer 0 ----
  hipMemsetAsync(flags, 0, 256*64*4, stream);
  lstm_fast<<<256,512,0,stream>>>(xp, wpk0, gg0, gb0, cg0, cb0, hA, tilesf, flags);

  // GEMM1: xp = h0 @ w_ih1^T
  gemm_f16<<<dim3(32,128),256,0,stream>>>(hA, w1h, xp, 16384, 4096, 1024, 0, nullptr);

  // ---- layer 1 ----
  hipMemsetAsync(flags, 0, 256*64*4, stream);
  lstm_fast<<<256,512,0,stream>>>(xp, wpk1, gg1, gb1, cg1, cb1, hA, tilesf, flags);

  k_bn2_stats<<<256,256,0,stream>>>(hA, stats2);
  k_bn2_fin<<<4,256,0,stream>>>(stats2, bn2g, bn2b, ss2);
  k_att1<<<1024,256,0,stream>>>(hA, ss2, wom, bom, uom, vu);
  k_att3<<<256,128,0,stream>>>(hA, ss2, vu, out);
}

// Round 15
// 5410.643 us; speedup vs baseline: 1.0502x; 1.0502x over previous
//
#include <hip/hip_runtime.h>
#include <hip/hip_bf16.h>

#define LN_EPS 1e-5f

typedef __attribute__((ext_vector_type(4))) float    f32x4;
typedef __attribute__((ext_vector_type(8))) _Float16 f16x8;
typedef __attribute__((ext_vector_type(4))) unsigned u32x4;

// fast transcendentals (v_exp based)
__device__ __forceinline__ float fsig(float x){
  return 1.0f/(1.0f + __expf(-x));
}
__device__ __forceinline__ float ftanh(float x){
  float xx = fminf(fmaxf(x, -15.f), 15.f);
  float e = __expf(2.f*xx);
  return (e - 1.f)/(e + 1.f);
}

__device__ __forceinline__ float agent_load_f(const float* p){
  return __hip_atomic_load((float*)p, __ATOMIC_RELAXED, __HIP_MEMORY_SCOPE_AGENT);
}
__device__ __forceinline__ void agent_store_f(float* p, float v){
  __hip_atomic_store(p, v, __ATOMIC_RELAXED, __HIP_MEMORY_SCOPE_AGENT);
}

// ---------------------------------------------------------------------------
// bn1
// ---------------------------------------------------------------------------
__global__ void k_bn1_stats(const float* __restrict__ x, float* __restrict__ stats){
  int tid = threadIdx.x;
  int cg = tid >> 3, ro = tid & 7;
  int c4 = cg * 4;
  float s[4] = {0,0,0,0}, q[4] = {0,0,0,0};
  int rbase = blockIdx.x * 64;
  for (int i = 0; i < 8; ++i){
    int row = rbase + i*8 + ro;
    f32x4 v = *(const f32x4*)(x + (size_t)row*128 + c4);
    #pragma unroll
    for (int e=0;e<4;e++){ s[e]+=v[e]; q[e]+=v[e]*v[e]; }
  }
  #pragma unroll
  for (int o=1;o<8;o<<=1){
    #pragma unroll
    for (int e=0;e<4;e++){ s[e]+=__shfl_xor(s[e],o); q[e]+=__shfl_xor(q[e],o); }
  }
  if (ro==0){
    #pragma unroll
    for (int e=0;e<4;e++){
      atomicAdd(&stats[c4+e], s[e]);
      atomicAdd(&stats[128+c4+e], q[e]);
    }
  }
}

__global__ void k_bn1_fin(const float* __restrict__ stats, const float* __restrict__ gamma,
                          const float* __restrict__ beta, float* __restrict__ ss){
  int c = threadIdx.x;
  if (c < 128){
    float N = 16384.0f;
    float mean = stats[c]/N;
    float var  = stats[128+c]/N - mean*mean;
    float scale = gamma[c] * rsqrtf(var + LN_EPS);
    ss[c] = scale;
    ss[128+c] = beta[c] - mean*scale;
  }
}

// f32 -> f16 elementwise
__global__ void k_cvt_f16(const float* __restrict__ s, _Float16* __restrict__ d, int n){
  for (int i = blockIdx.x*blockDim.x + threadIdx.x; i < n; i += gridDim.x*blockDim.x)
    d[i] = (_Float16)s[i];
}

// pack whh [2][2048][512] f32 -> fragment-linear f16
// wpk[(dir*4+gate)][kt=16][c16=32][lane=64][8]
__global__ void k_pack_whh(const float* __restrict__ whh, _Float16* __restrict__ wpk){
  size_t i = (size_t)blockIdx.x*256 + threadIdx.x;     // over 2*2048*512
  int k = (int)(i & 511);
  size_t ci = i >> 9;
  int col = (int)(ci & 2047);
  int dirr = (int)(ci >> 11);
  int gate = col >> 9, cig = col & 511, c16 = cig >> 4, lc = cig & 15;
  int kt = k >> 5, ksub = k & 31, hi = ksub >> 3, j = ksub & 7;
  size_t dst = ((((size_t)(dirr*4+gate)*16 + kt)*32 + c16)*64 + (hi*16+lc))*8 + j;
  wpk[dst] = (_Float16)whh[i];
}

// ---------------------------------------------------------------------------
// Single-pass f16 GEMM: C[M][N] = A[M][K] * B[N][K]^T, C f16, fp32 accumulate.
// ---------------------------------------------------------------------------
__global__ __launch_bounds__(256) void gemm_f16(const float* __restrict__ A,
                                                const _Float16* __restrict__ Bp,
                                                _Float16* __restrict__ C,
                                                int M, int N, int K,
                                                int a_mode, const float* __restrict__ ss){
  __shared__ __align__(16) _Float16 As[128*32];
  __shared__ __align__(16) _Float16 Bs[128*32];
  int n0 = blockIdx.x * 128, m0 = blockIdx.y * 128;
  int tid = threadIdx.x, lane = tid & 63, wave = tid >> 6;
  int wm = wave >> 1, wn = wave & 1;
  f32x4 acc[4][4] = {};
  int r = tid >> 2, sseg = tid & 3;
  for (int kt = 0; kt < K; kt += 32){
    #pragma unroll
    for (int half = 0; half < 2; ++half){
      int m = m0 + half*64 + r;
      const float* src;
      if (a_mode){
        int t = m >> 5, b = m & 31;
        src = A + ((size_t)(b*512 + t))*128 + kt + sseg*8;
      } else {
        src = A + (size_t)m*K + kt + sseg*8;
      }
      f32x4 v0 = *(const f32x4*)src;
      f32x4 v1 = *(const f32x4*)(src + 4);
      f16x8 vh;
      #pragma unroll
      for (int e=0;e<4;e++){
        float f0 = v0[e], f1 = v1[e];
        if (a_mode){
          int k = kt + sseg*8;
          f0 = f0*ss[k+e]   + ss[128+k+e];
          f1 = f1*ss[k+4+e] + ss[128+k+4+e];
        }
        vh[e] = (_Float16)f0; vh[4+e] = (_Float16)f1;
      }
      *(f16x8*)&As[(half*64+r)*32 + sseg*8] = vh;
      u32x4 bv = *(const u32x4*)(Bp + (size_t)(n0 + half*64 + r)*K + kt + sseg*8);
      *(u32x4*)&Bs[(half*64+r)*32 + sseg*8] = bv;
    }
    __syncthreads();
    f16x8 af[4], bf[4];
    int k8 = (lane >> 4) * 8;
    int ra = wm*64 + (lane & 15), rb = wn*64 + (lane & 15);
    #pragma unroll
    for (int mi=0;mi<4;mi++) af[mi] = *(const f16x8*)&As[(ra + mi*16)*32 + k8];
    #pragma unroll
    for (int ni=0;ni<4;ni++) bf[ni] = *(const f16x8*)&Bs[(rb + ni*16)*32 + k8];
    #pragma unroll
    for (int mi=0;mi<4;mi++)
      #pragma unroll
      for (int ni=0;ni<4;ni++)
        acc[mi][ni] = __builtin_amdgcn_mfma_f32_16x16x32_f16(af[mi], bf[ni], acc[mi][ni], 0, 0, 0);
    __syncthreads();
  }
  #pragma unroll
  for (int mi=0;mi<4;mi++)
    #pragma unroll
    for (int ni=0;ni<4;ni++){
      int col  = n0 + wn*64 + ni*16 + (lane & 15);
      int row0 = m0 + wm*64 + mi*16 + (lane >> 4)*4;
      #pragma unroll
      for (int rr=0;rr<4;rr++)
        C[(size_t)(row0+rr)*N + col] = (_Float16)acc[mi][ni][rr];
    }
}

// ---------------------------------------------------------------------------
// LSTM, weights-in-registers, small-group exchange (R13 optimum, final):
// 256 blocks = bq(16) x dir(2) x gate(4) x half(2); 2 batch rows, 256 cols.
// Weights: 32 f16x8 = 128 VGPRs, asm "+v" pinned.
// chunk layout (floats): [2 b][256 cols] + [2 b][2 stats]  (stride 516)
// ---------------------------------------------------------------------------
#define CHUNK 516

__global__ __launch_bounds__(512, 1) void lstm_fast(
    const _Float16* __restrict__ xp,     // [16384][4096]
    const _Float16* __restrict__ wpk,    // [8 slices][16][32][64][8]
    const float* __restrict__ gg, const float* __restrict__ gb,   // [2][2048]
    const float* __restrict__ cgam, const float* __restrict__ cbet, // [2][512]
    float* __restrict__ out,             // [16384][1024]
    float* __restrict__ tf,              // [32grp][2buf][8chunk][CHUNK]
    unsigned* __restrict__ flags)        // [256*64]
{
  int blk = blockIdx.x;
  int sub = blk & 15;                    // (dir,gate,half) -> XCD spread
  int bq = blk >> 4;                     // 0..15, 2 batch rows each
  int dir = sub >> 3, gate = (sub >> 1) & 3, half = sub & 1;
  int tid = threadIdx.x, lane = tid & 63, wv = tid >> 6;
  int b0 = bq * 2;
  int grp = bq*2 + dir;                  // 0..31
  int blkbase = (bq << 4) | (dir << 3);
  int own_sub = gate*2 + half;           // 0..7

  __shared__ __align__(16) _Float16 hfrag[16*64*8];   // 16KB A-fragments (rows 0..1 used)
  __shared__ float c_s[2][512];                        // 4KB
  __shared__ float red[8][2][2];
  __shared__ float redc[8][2][2];
  __shared__ float lnstat[8][2];

  for (int i = tid; i < 16*64*8; i += 512) hfrag[i] = (_Float16)0.f;
  for (int i = tid; i < 2*512;  i += 512) c_s[i>>9][i&511] = 0.f;
  __syncthreads();

  // ---- hoist loop-invariant LN/cell params ----
  int j = tid;
  float g0s = gg[dir*2048 + j],        g0b = gb[dir*2048 + j];
  float g1s = gg[dir*2048 + 512 + j],  g1b = gb[dir*2048 + 512 + j];
  float g2s = gg[dir*2048 + 1024 + j], g2b = gb[dir*2048 + 1024 + j];
  float g3s = gg[dir*2048 + 1536 + j], g3b = gb[dir*2048 + 1536 + j];
  float cgv = cgam[dir*512 + j],       cbv = cbet[dir*512 + j];

  // ---- load weight slice into registers: c16 = half*16 + wv*2 + {0,1} ----
  const _Float16* wbase = wpk + (size_t)(dir*4 + gate) * (16*32*64*8);
  int c16a = half*16 + wv*2, c16b = c16a + 1;
  f16x8 wA[16], wB[16];
  #pragma unroll
  for (int kt = 0; kt < 16; ++kt){
    wA[kt] = *(const f16x8*)&wbase[(((size_t)kt*32 + c16a)*64 + lane)*8];
    wB[kt] = *(const f16x8*)&wbase[(((size_t)kt*32 + c16b)*64 + lane)*8];
  }

  for (int t = 0; t < 512; ++t){
    // pin all 32 fragments: asm "redefines" them each iteration -> no remat
    asm volatile("" : "+v"(wA[0]), "+v"(wA[1]), "+v"(wA[2]), "+v"(wA[3]),
                      "+v"(wA[4]), "+v"(wA[5]), "+v"(wA[6]), "+v"(wA[7]));
    asm volatile("" : "+v"(wA[8]), "+v"(wA[9]), "+v"(wA[10]), "+v"(wA[11]),
                      "+v"(wA[12]), "+v"(wA[13]), "+v"(wA[14]), "+v"(wA[15]));
    asm volatile("" : "+v"(wB[0]), "+v"(wB[1]), "+v"(wB[2]), "+v"(wB[3]),
                      "+v"(wB[4]), "+v"(wB[5]), "+v"(wB[6]), "+v"(wB[7]));
    asm volatile("" : "+v"(wB[8]), "+v"(wB[9]), "+v"(wB[10]), "+v"(wB[11]),
                      "+v"(wB[12]), "+v"(wB[13]), "+v"(wB[14]), "+v"(wB[15]));
    int pos = dir ? (511 - t) : t;
    int buf = t & 1;
    // ---- xp loads (independent of h) ----
    float xv0[2], xv1[2];
    if (lane < 16){
      const _Float16* xb = xp + (size_t)(pos*32 + b0)*4096 + dir*2048 + gate*512 + half*256;
      #pragma unroll
      for (int r = 0; r < 2; ++r){
        xv0[r] = (float)xb[(size_t)r*4096 + (wv*2)*16 + lane];
        xv1[r] = (float)xb[(size_t)r*4096 + (wv*2)*16 + lane + 16];
      }
    }
    // ---- GEMV: pure-register MFMA (32 MFMA) ----
    f32x4 acc0 = {}, acc1 = {};
    #pragma unroll
    for (int kt = 0; kt < 16; ++kt){
      f16x8 afrag = *(const f16x8*)&hfrag[(kt*64 + lane)*8];
      acc0 = __builtin_amdgcn_mfma_f32_16x16x32_f16(afrag, wA[kt], acc0, 0, 0, 0);
      acc1 = __builtin_amdgcn_mfma_f32_16x16x32_f16(afrag, wB[kt], acc1, 0, 0, 0);
    }
    // ---- pre-LN + publish chunk [2b][256col] + stats partials ----
    float* chk = tf + ((size_t)(grp*2 + buf)*8 + own_sub)*CHUNK;
    float s[2] = {0,0}, q[2] = {0,0};
    if (lane < 16){
      int cA = (wv*2)*16 + lane, cB = cA + 16;     // local cols 0..255
      #pragma unroll
      for (int r = 0; r < 2; ++r){
        float v0 = acc0[r] + xv0[r];
        float v1 = acc1[r] + xv1[r];
        agent_store_f(chk + r*256 + cA, v0);
        agent_store_f(chk + r*256 + cB, v1);
        s[r] = v0 + v1; q[r] = v0*v0 + v1*v1;
      }
    }
    #pragma unroll
    for (int o = 1; o < 16; o <<= 1){
      #pragma unroll
      for (int r = 0; r < 2; ++r){ s[r] += __shfl_xor(s[r], o); q[r] += __shfl_xor(q[r], o); }
    }
    if (lane == 0){
      #pragma unroll
      for (int r = 0; r < 2; ++r){ red[wv][r][0] = s[r]; red[wv][r][1] = q[r]; }
    }
    __syncthreads();                 // S1: red ready
    if (tid < 4){
      int b = tid >> 1, wh = tid & 1;
      float S = 0.f;
      #pragma unroll
      for (int w8 = 0; w8 < 8; ++w8) S += red[w8][b][wh];
      agent_store_f(chk + 512 + b*2 + wh, S);
    }
    asm volatile("s_waitcnt vmcnt(0)" ::: "memory");
    __syncthreads();                 // S2: all stores drained
    if (tid == 0)
      __hip_atomic_store(&flags[blk*64], (unsigned)(t+1), __ATOMIC_RELAXED, __HIP_MEMORY_SCOPE_AGENT);
    if (tid < 7){
      int idx = tid < own_sub ? tid : tid + 1;
      int sblk = blkbase + idx;
      while (__hip_atomic_load(&flags[sblk*64], __ATOMIC_RELAXED, __HIP_MEMORY_SCOPE_AGENT)
             < (unsigned)(t+1)){ }
    }
    __syncthreads();                 // S3: all sibling data visible
    // ---- read: tiles (all threads, 8 loads) + stats (tid<8) ----
    const float* gbase = tf + ((size_t)(grp*2 + buf)*8)*CHUNK;
    int hf = j >> 8, cc = j & 255;       // half, col-in-half for column j
    float p[4][2];
    #pragma unroll
    for (int g = 0; g < 4; ++g){
      const float* cp = gbase + (size_t)(g*2 + hf)*CHUNK + cc;
      #pragma unroll
      for (int b = 0; b < 2; ++b) p[g][b] = agent_load_f(cp + b*256);
    }
    if (tid < 8){
      int g = tid >> 1, b = tid & 1;
      float S = 0.f, Q = 0.f;
      #pragma unroll
      for (int hh = 0; hh < 2; ++hh){
        S += agent_load_f(gbase + (size_t)(g*2 + hh)*CHUNK + 512 + b*2);
        Q += agent_load_f(gbase + (size_t)(g*2 + hh)*CHUNK + 512 + b*2 + 1);
      }
      float mean = S*(1.0f/512.0f);
      float var  = Q*(1.0f/512.0f) - mean*mean;
      lnstat[tid][0] = mean; lnstat[tid][1] = rsqrtf(var + LN_EPS);
    }
    __syncthreads();                 // S4: lnstat ready (p already in regs)
    // ---- LN + cell update (2 b per thread) ----
    float cs[2], cq2[2], ov[2], cnv[2];
    #pragma unroll
    for (int b = 0; b < 2; ++b){
      float pi = (p[0][b] - lnstat[0*2+b][0])*lnstat[0*2+b][1]*g0s + g0b;
      float pf = (p[1][b] - lnstat[1*2+b][0])*lnstat[1*2+b][1]*g1s + g1b;
      float pv = (p[2][b] - lnstat[2*2+b][0])*lnstat[2*2+b][1]*g2s + g2b;
      ov[b]    = (p[3][b] - lnstat[3*2+b][0])*lnstat[3*2+b][1]*g3s + g3b;
      float cn = fsig(pf)*c_s[b][j] + fsig(pi)*ftanh(pv);
      c_s[b][j] = cn; cnv[b] = cn;
      cs[b] = cn; cq2[b] = cn*cn;
    }
    #pragma unroll
    for (int o = 1; o < 64; o <<= 1){
      #pragma unroll
      for (int b = 0; b < 2; ++b){ cs[b] += __shfl_xor(cs[b], o); cq2[b] += __shfl_xor(cq2[b], o); }
    }
    if (lane == 0){
      #pragma unroll
      for (int b = 0; b < 2; ++b){ redc[wv][b][0] = cs[b]; redc[wv][b][1] = cq2[b]; }
    }
    __syncthreads();                 // S5: redc ready
    #pragma unroll
    for (int b = 0; b < 2; ++b){
      float S = 0.f, Q = 0.f;
      #pragma unroll
      for (int w8 = 0; w8 < 8; ++w8){ S += redc[w8][b][0]; Q += redc[w8][b][1]; }
      float mean = S*(1.0f/512.0f);
      float var  = Q*(1.0f/512.0f) - mean*mean;
      float rstd = rsqrtf(var + LN_EPS);
      float cl = (cnv[b] - mean)*rstd*cgv + cbv;
      float hv = fsig(ov[b]) * ftanh(cl);
      hfrag[(((j >> 5)*64) + ((j & 31) >> 3)*16 + b)*8 + (j & 7)] = (_Float16)hv;
      if (own_sub == 0)
        out[(size_t)(pos*32 + b0 + b)*1024 + dir*512 + j] = hv;
    }
    __syncthreads();                 // S6: hfrag ready for next step
  }
}

// ---------------------------------------------------------------------------
__global__ void k_bn2_stats(const float* __restrict__ h1, float* __restrict__ stats){
  int tid = threadIdx.x;
  int c4 = tid*4;
  float s[4]={0,0,0,0}, q[4]={0,0,0,0};
  int rbase = blockIdx.x*64;
  for (int i=0;i<64;i++){
    f32x4 v = *(const f32x4*)(h1 + (size_t)(rbase+i)*1024 + c4);
    #pragma unroll
    for (int e=0;e<4;e++){ s[e]+=v[e]; q[e]+=v[e]*v[e]; }
  }
  #pragma unroll
  for (int e=0;e<4;e++){
    atomicAdd(&stats[c4+e], s[e]);
    atomicAdd(&stats[1024+c4+e], q[e]);
  }
}

__global__ void k_bn2_fin(const float* __restrict__ stats, const float* __restrict__ gamma,
                          const float* __restrict__ beta, float* __restrict__ ss){
  int c = blockIdx.x*256 + threadIdx.x;
  if (c < 1024){
    float N = 16384.0f;
    float mean = stats[c]/N;
    float var  = stats[1024+c]/N - mean*mean;
    float scale = gamma[c] * rsqrtf(var + LN_EPS);
    ss[c] = scale;
    ss[1024+c] = beta[c] - mean*scale;
  }
}

__global__ void k_att1(const float* __restrict__ h1, const float* __restrict__ ss,
                       const float* __restrict__ wom, const float* __restrict__ bom,
                       const float* __restrict__ uom, float* __restrict__ vu){
  __shared__ float tmp[4][64];
  int tid = threadIdx.x, wave = tid >> 6, ln = tid & 63;
  int part = ln/20, a = ln - part*20;
  bool active = (part < 3);
  for (int rr = 0; rr < 4; ++rr){
    int row = blockIdx.x*16 + wave*4 + rr;
    float acc = 0.0f;
    if (active){
      int n0 = part*342, n1 = (part==2) ? 1024 : (n0+342);
      for (int n = n0; n < n1; ++n){
        float hv = h1[(size_t)row*1024 + n]*ss[n] + ss[1024+n];
        acc += hv * wom[n*20 + a];
      }
    }
    tmp[wave][ln] = acc;
    __syncthreads();
    float pv = 0.0f;
    if (ln < 20){
      float v = tanhf(tmp[wave][ln] + tmp[wave][ln+20] + tmp[wave][ln+40] + bom[ln]);
      pv = v*uom[ln];
    }
    #pragma unroll
    for (int o=1;o<32;o<<=1) pv += __shfl_xor(pv, o);
    if (ln == 0) vu[row] = pv;
    __syncthreads();
  }
}

__global__ void k_att3(const float* __restrict__ h1, const float* __restrict__ ss,
                       const float* __restrict__ vu, float* __restrict__ out){
  __shared__ float al[512];
  __shared__ float red[4];
  int tid = threadIdx.x;
  int b = blockIdx.x >> 3, ch = blockIdx.x & 7;
  for (int t = tid; t < 512; t += 128) al[t] = vu[t*32 + b];
  __syncthreads();
  float m = -1e30f;
  for (int t = tid; t < 512; t += 128) m = fmaxf(m, al[t]);
  #pragma unroll
  for (int o=1;o<64;o<<=1) m = fmaxf(m, __shfl_xor(m,o));
  if ((tid & 63) == 0) red[tid>>6] = m;
  __syncthreads();
  m = fmaxf(red[0], red[1]);
  float s = 0.0f;
  for (int t = tid; t < 512; t += 128){ float e = expf(al[t]-m); al[t] = e; s += e; }
  #pragma unroll
  for (int o=1;o<64;o<<=1) s += __shfl_xor(s,o);
  if ((tid & 63) == 0) red[2 + (tid>>6)] = s;
  __syncthreads();
  float inv = 1.0f / (red[2] + red[3]);
  int n = ch*128 + tid;
  float acc = 0.0f;
  #pragma unroll 4
  for (int t = 0; t < 512; ++t) acc += al[t]*h1[(size_t)(t*32+b)*1024 + n];
  out[b*1024 + n] = acc*inv*ss[n] + ss[1024+n];
}

// ---------------------------------------------------------------------------
extern "C" void kernel_launch(void* const* d_in, const int* in_sizes, int n_in,
                              void* d_out, int out_size, void* d_ws, size_t ws_size,
                              hipStream_t stream){
  const float* x    = (const float*)d_in[0];
  const float* bn1g = (const float*)d_in[1];
  const float* bn1b = (const float*)d_in[2];
  const float* bn2g = (const float*)d_in[3];
  const float* bn2b = (const float*)d_in[4];
  const float* wih0 = (const float*)d_in[5];
  const float* whh0 = (const float*)d_in[6];
  const float* gg0  = (const float*)d_in[7];
  const float* gb0  = (const float*)d_in[8];
  const float* cg0  = (const float*)d_in[9];
  const float* cb0  = (const float*)d_in[10];
  const float* wih1 = (const float*)d_in[11];
  const float* whh1 = (const float*)d_in[12];
  const float* gg1  = (const float*)d_in[13];
  const float* gb1  = (const float*)d_in[14];
  const float* cg1  = (const float*)d_in[15];
  const float* cb1  = (const float*)d_in[16];
  const float* wom  = (const float*)d_in[17];
  const float* bom  = (const float*)d_in[18];
  const float* uom  = (const float*)d_in[19];
  float* out = (float*)d_out;

  char* w = (char*)d_ws;
  size_t off = 0;
  auto take = [&](size_t bytes)->void*{
    void* p = w + off;
    off += (bytes + 255) & ~(size_t)255;
    return p;
  };
  _Float16* xp = (_Float16*)take(16384ull*4096*2);      // 128 MB
  float* hA = (float*)take(16384ull*1024*4);            // 64 MB
  _Float16* w0h = (_Float16*)take(4096ull*128*2);       // 1 MB
  _Float16* w1h = (_Float16*)take(4096ull*1024*2);      // 8 MB
  _Float16* wpk0 = (_Float16*)take(2ull*2048*512*2);    // 4 MB
  _Float16* wpk1 = (_Float16*)take(2ull*2048*512*2);    // 4 MB
  float* tilesf = (float*)take(32ull*2*8*CHUNK*4);      // ~1.06 MB
  unsigned* flags = (unsigned*)take(256ull*64*4);       // 64 KB
  float* stats1 = (float*)take(256*4);
  float* ss1    = (float*)take(256*4);
  float* stats2 = (float*)take(2048*4);
  float* ss2    = (float*)take(2048*4);
  float* vu     = (float*)take(16384ull*4);
  (void)ws_size; (void)in_sizes; (void)n_in; (void)out_size;

  hipMemsetAsync(stats1, 0, 256*4, stream);
  hipMemsetAsync(stats2, 0, 2048*4, stream);

  k_bn1_stats<<<256,256,0,stream>>>(x, stats1);
  k_bn1_fin<<<1,128,0,stream>>>(stats1, bn1g, bn1b, ss1);
  k_cvt_f16<<<256,256,0,stream>>>(wih0, w0h, 4096*128);
  k_cvt_f16<<<2048,256,0,stream>>>(wih1, w1h, 4096*1024);
  k_pack_whh<<<8192,256,0,stream>>>(whh0, wpk0);
  k_pack_whh<<<8192,256,0,stream>>>(whh1, wpk1);

  // GEMM0: xp = bn1(x) @ w_ih0^T
  gemm_f16<<<dim3(32,128),256,0,stream>>>(x, w0h, xp, 16384, 4096, 128, 1, ss1);

  // ---- layer 0 ----
  hipMemsetAsync(flags, 0, 256*64*4, stream);
  lstm_fast<<<256,512,0,stream>>>(xp, wpk0, gg0, gb0, cg0, cb0, hA, tilesf, flags);

  // GEMM1: xp = h0 @ w_ih1^T
  gemm_f16<<<dim3(32,128),256,0,stream>>>(hA, w1h, xp, 16384, 4096, 1024, 0, nullptr);

  // ---- layer 1 ----
  hipMemsetAsync(flags, 0, 256*64*4, stream);
  lstm_fast<<<256,512,0,stream>>>(xp, wpk1, gg1, gb1, cg1, cb1, hA, tilesf, flags);

  k_bn2_stats<<<256,256,0,stream>>>(hA, stats2);
  k_bn2_fin<<<4,256,0,stream>>>(stats2, bn2g, bn2b, ss2);
  k_att1<<<1024,256,0,stream>>>(hA, ss2, wom, bom, uom, vu);
  k_att3<<<256,128,0,stream>>>(hA, ss2, vu, out);
}